// Round 8
// baseline (233.830 us; speedup 1.0000x reference)
//
#include <hip/hip_runtime.h>

typedef float  f32x16 __attribute__((ext_vector_type(16)));
typedef short  short8 __attribute__((ext_vector_type(8)));
typedef unsigned short u16;
typedef unsigned int   u32;

#define LOG2PI_F 1.8378770664093453f

__device__ __forceinline__ u16 f2bf(float f) {
  u32 u = __builtin_bit_cast(u32, f);
  u32 r = (u + 0x7FFFu + ((u >> 16) & 1u)) >> 16;
  return (u16)r;
}

// ---------------------------------------------------------------------------
// K0: emissions. E[t,j] = exp(log_em[t,j] - s_t), s_t = max_j log_em[t,j].
// ---------------------------------------------------------------------------
__global__ __launch_bounds__(256) void emis_kernel(
    const float* __restrict__ Y, const float* __restrict__ mu,
    const float* __restrict__ rlv, int T,
    float* __restrict__ E, float* __restrict__ Spart)
{
  int j  = threadIdx.x & 31;
  int ts = threadIdx.x >> 5;  // 0..7

  float muv[16], iv[16];
  float slv = 0.f;
  const float4* mp = (const float4*)(mu  + (size_t)j * 16);
  const float4* rp = (const float4*)(rlv + (size_t)j * 16);
#pragma unroll
  for (int q = 0; q < 4; ++q) {
    float4 m4 = mp[q], r4 = rp[q];
    float mm[4] = {m4.x, m4.y, m4.z, m4.w};
    float rr[4] = {r4.x, r4.y, r4.z, r4.w};
#pragma unroll
    for (int e = 0; e < 4; ++e) {
      float lv = fminf(fmaxf(rr[e], -6.f), 6.f);
      muv[4*q+e] = mm[e];
      iv[4*q+e]  = __expf(-lv);
      slv += lv;
    }
  }
  float base_c = 16.f * LOG2PI_F + slv;

  float sacc = 0.f;
  for (int p2 = 0; p2 < 8; ++p2) {
    int t = blockIdx.x * 64 + p2 * 8 + ts;
    if (t < T) {
      float quad = 0.f;
      const float4* yp = (const float4*)(Y + (size_t)t * 16);
#pragma unroll
      for (int q = 0; q < 4; ++q) {
        float4 y4 = yp[q];
        float yy[4] = {y4.x, y4.y, y4.z, y4.w};
#pragma unroll
        for (int e = 0; e < 4; ++e) {
          float d = yy[e] - muv[4*q+e];
          quad = fmaf(d * d, iv[4*q+e], quad);
        }
      }
      float lem = -0.5f * (base_c + quad);
      float mx = lem;
#pragma unroll
      for (int m = 16; m >= 1; m >>= 1) mx = fmaxf(mx, __shfl_xor(mx, m, 32));
      E[(size_t)t * 32 + j] = __expf(lem - mx);
      if (j == 0) sacc += mx;
    }
  }
  __shared__ float sred[8];
  if (j == 0) sred[ts] = sacc;
  __syncthreads();
  if (threadIdx.x == 0) {
    float s = 0.f;
#pragma unroll
    for (int k = 0; k < 8; ++k) s += sred[k];
    Spart[blockIdx.x] = s;
  }
}

// ---------------------------------------------------------------------------
// Prep: Wfrag = A-operand fragments of W/ln2 (bf16), bprime = b/ln2.
// ---------------------------------------------------------------------------
__global__ __launch_bounds__(256) void prep_kernel(
    const float* __restrict__ W, const float* __restrict__ b,
    u16* __restrict__ Wfrag, float* __restrict__ bprime)
{
  const float INVLN2 = 1.4426950408889634f;
  int idx = blockIdx.x * 256 + threadIdx.x;
  if (idx < 16384) {
    int i = idx >> 9, rem = idx & 511, l = rem >> 3, e = rem & 7;
    int j = l & 31, h = l >> 5;
    Wfrag[idx] = f2bf(W[i * 512 + j * 16 + h * 8 + e] * INVLN2);
  }
  if (idx < 1024) bprime[idx] = b[idx] * INVLN2;
}

// ---------------------------------------------------------------------------
// Shared primitives (hardware-verified rounds 0-7).
// ---------------------------------------------------------------------------
__device__ __forceinline__ void acc_to_bops(const f32x16& acc, uint4& B1, uint4& B2) {
  u32 pk[8];
#pragma unroll
  for (int q = 0; q < 8; ++q) {
    u32 r;
    asm("v_cvt_pk_bf16_f32 %0, %1, %2" : "=v"(r) : "v"(acc[2*q]), "v"(acc[2*q+1]));
    pk[q] = r;
  }
  asm("v_permlane32_swap_b32 %0, %1" : "+v"(pk[0]), "+v"(pk[2]));
  asm("v_permlane32_swap_b32 %0, %1" : "+v"(pk[1]), "+v"(pk[3]));
  B1 = make_uint4(pk[0], pk[1], pk[2], pk[3]);
  asm("v_permlane32_swap_b32 %0, %1" : "+v"(pk[4]), "+v"(pk[6]));
  asm("v_permlane32_swap_b32 %0, %1" : "+v"(pk[5]), "+v"(pk[7]));
  B2 = make_uint4(pk[4], pk[5], pk[6], pk[7]);
}

__device__ __forceinline__ void renorm(f32x16& acc, float& Eacc) {
  float m = acc[0];
#pragma unroll
  for (int r = 1; r < 16; ++r) m = fmaxf(m, acc[r]);
#pragma unroll
  for (int off = 32; off >= 1; off >>= 1) m = fmaxf(m, __shfl_xor(m, off, 64));
  if (m > 0.f) {
    int ex;
    frexpf(m, &ex);
    float sc = ldexpf(1.f, -ex);
#pragma unroll
    for (int r = 0; r < 16; ++r) acc[r] *= sc;
    Eacc += (float)ex;
  }
}

__device__ __forceinline__ void bmat2_batch(
    const short8* wf, int ib0, short8 xf, const float* __restrict__ bprime,
    int h, const float* ee, u32* cw /* [32] */)
{
  f32x16 a[4];
#pragma unroll
  for (int e = 0; e < 4; ++e) {
    f32x16 c;
#pragma unroll
    for (int qd = 0; qd < 4; ++qd) {
      float4 b4 = *(const float4*)(bprime + (ib0 + e) * 32 + 4 * h + 8 * qd);
      c[4*qd+0] = b4.x; c[4*qd+1] = b4.y; c[4*qd+2] = b4.z; c[4*qd+3] = b4.w;
    }
    a[e] = __builtin_amdgcn_mfma_f32_32x32x16_bf16(wf[e], xf, c, 0, 0, 0);
  }
#pragma unroll
  for (int e = 0; e < 4; ++e) {
    float s = 0.f;
#pragma unroll
    for (int r = 0; r < 16; ++r) { float p = exp2f(a[e][r]); a[e][r] = p; s += p; }
    float s2 = s, s3 = s;
    asm("v_permlane32_swap_b32 %0, %1" : "+v"(s2), "+v"(s3));
    float rv = __builtin_amdgcn_rcpf(s2 + s3);
#pragma unroll
    for (int r = 0; r < 16; ++r) a[e][r] *= rv;
  }
#pragma unroll
  for (int r = 0; r < 16; ++r) {
    float e0 = a[0][r] * ee[r], e1 = a[1][r] * ee[r];
    float e2 = a[2][r] * ee[r], e3 = a[3][r] * ee[r];
    u32 w0, w1;
    asm("v_cvt_pk_bf16_f32 %0, %1, %2" : "=v"(w0) : "v"(e0), "v"(e1));
    asm("v_cvt_pk_bf16_f32 %0, %1, %2" : "=v"(w1) : "v"(e2), "v"(e3));
    cw[r*2+0] = w0; cw[r*2+1] = w1;
  }
}

// ---------------------------------------------------------------------------
// fused1w: ONE WAVE per block, block owns 64 consecutive t. No cross-wave
// anything, no required barriers. Per 32-t group:
//   Phase P: produce the 32 B-matrices (verified bmat2 math, all 32 i per
//            wave, wf[32] resident) into private 64KB LDS in the verified
//            matrix image: uint4 lds4[tc*128 + c].
//   Phase C: chain the 32 matrices (verified step): lane reads chunks
//            2l / 2l+1 of matrix k, renorm every 8.
// Level structure = exact round-5 (absmax 0.0): 2048 chains of 64.
// ---------------------------------------------------------------------------
__global__ __launch_bounds__(64) void fused1w_kernel(
    const float* __restrict__ X, const float* __restrict__ E,
    const u16* __restrict__ Wfrag, const float* __restrict__ bprime,
    int T, u16* __restrict__ Sg, float* __restrict__ Eg)
{
  __shared__ __align__(16) uint4 lds4[4096];  // 64 KB: 32 matrices x 128 uint4
  int l = threadIdx.x, tc = l & 31, h = l >> 5;

  short8 wf[32];
#pragma unroll
  for (int it = 0; it < 32; ++it)
    wf[it] = *(const short8*)(Wfrag + ((size_t)it * 64 + l) * 8);

  f32x16 acc, zero16;
#pragma unroll
  for (int r = 0; r < 16; ++r) {
    int row = (r & 3) + 8 * (r >> 2) + 4 * h;
    acc[r]  = (row == (l & 31)) ? 1.f : 0.f;
    zero16[r] = 0.f;
  }
  float Eacc = 0.f;

  for (int grp = 0; grp < 2; ++grp) {
    int tglob = blockIdx.x * 64 + grp * 32 + tc;

    // ---- Phase P: production (verbatim bmat2 math) ----
    float4 xa = *(const float4*)(X + (size_t)tglob * 16 + 8 * h);
    float4 xb = *(const float4*)(X + (size_t)tglob * 16 + 8 * h + 4);
    u32 xp0, xp1, xp2, xp3;
    asm("v_cvt_pk_bf16_f32 %0, %1, %2" : "=v"(xp0) : "v"(xa.x), "v"(xa.y));
    asm("v_cvt_pk_bf16_f32 %0, %1, %2" : "=v"(xp1) : "v"(xa.z), "v"(xa.w));
    asm("v_cvt_pk_bf16_f32 %0, %1, %2" : "=v"(xp2) : "v"(xb.x), "v"(xb.y));
    asm("v_cvt_pk_bf16_f32 %0, %1, %2" : "=v"(xp3) : "v"(xb.z), "v"(xb.w));
    uint4 xu = make_uint4(xp0, xp1, xp2, xp3);
    short8 xf = __builtin_bit_cast(short8, xu);

    float ee[16];
#pragma unroll
    for (int qd = 0; qd < 4; ++qd) {
      float4 eq = *(const float4*)(E + (size_t)tglob * 32 + 4 * h + 8 * qd);
      ee[4*qd+0] = eq.x; ee[4*qd+1] = eq.y; ee[4*qd+2] = eq.z; ee[4*qd+3] = eq.w;
    }

#pragma unroll
    for (int b = 0; b < 4; ++b) {
      u32 cA[32], cB[32];
      bmat2_batch(wf + 8*b,     8*b,     xf, bprime, h, ee, cA);
      bmat2_batch(wf + 8*b + 4, 8*b + 4, xf, bprime, h, ee, cB);
#pragma unroll
      for (int qd = 0; qd < 4; ++qd) {
#pragma unroll
        for (int pp = 0; pp < 4; ++pp) {
          int r = 4*qd + pp;
          int j = 4*h + 8*qd + pp;
          uint4 v = make_uint4(cA[2*r], cA[2*r+1], cB[2*r], cB[2*r+1]);
          if (tglob == 0) {
            u32 i0 = 8*b;
            u32 w0 = ((i0+0 == (u32)j) ? 0x3F80u : 0u) | (((i0+1 == (u32)j) ? 0x3F80u : 0u) << 16);
            u32 w1 = ((i0+2 == (u32)j) ? 0x3F80u : 0u) | (((i0+3 == (u32)j) ? 0x3F80u : 0u) << 16);
            u32 w2 = ((i0+4 == (u32)j) ? 0x3F80u : 0u) | (((i0+5 == (u32)j) ? 0x3F80u : 0u) << 16);
            u32 w3 = ((i0+6 == (u32)j) ? 0x3F80u : 0u) | (((i0+7 == (u32)j) ? 0x3F80u : 0u) << 16);
            v = make_uint4(w0, w1, w2, w3);
          }
          int c = (j + 32 * (b & 1)) * 2 + (b >> 1);   // exact verified chunk index
          lds4[tc * 128 + c] = v;
        }
      }
    }
    __syncthreads();  // 1-wave block: cheap fence, forces LDS drain

    // ---- Phase C: chain the 32 matrices (verbatim verified step) ----
#pragma unroll 4
    for (int k = 0; k < 32; ++k) {
      uint4 A1 = lds4[k * 128 + 2 * l];
      uint4 A2 = lds4[k * 128 + 2 * l + 1];
      uint4 B1, B2;
      acc_to_bops(acc, B1, B2);
      f32x16 t1 = __builtin_amdgcn_mfma_f32_32x32x16_bf16(
          __builtin_bit_cast(short8, A1), __builtin_bit_cast(short8, B1), zero16, 0, 0, 0);
      acc = __builtin_amdgcn_mfma_f32_32x32x16_bf16(
          __builtin_bit_cast(short8, A2), __builtin_bit_cast(short8, B2), t1, 0, 0, 0);
      if ((k & 7) == 7) renorm(acc, Eacc);
    }
    __syncthreads();  // before next group's production overwrites LDS
  }

  // ---- epilogue: verbatim verified out_frags write ----
  int col = l & 31;
#pragma unroll
  for (int r = 0; r < 16; ++r) {
    int row = (r & 3) + 8 * (r >> 2) + 4 * h;
    int flat = (row + 32 * ((col >> 3) & 1)) * 16 + ((col >> 4) << 3) + (col & 7);
    Sg[(size_t)blockIdx.x * 1024 + flat] = f2bf(acc[r]);
  }
  if (l == 0) Eg[blockIdx.x] = Eacc;
}

// ---------------------------------------------------------------------------
// Chain kernel (levels 2-3; verified multi-wave form from round 7).
// Matrix-major: chunk c of matrix m at uint4 index c + m*128.
// ---------------------------------------------------------------------------
__global__ void chain_kernel(
    const uint4* __restrict__ in_frags, const float* __restrict__ in_E,
    int nchains, int mpb, u16* __restrict__ out_frags,
    float* __restrict__ out_E, float* __restrict__ out_final)
{
  int w = threadIdx.x >> 6, l = threadIdx.x & 63;
  int cid = blockIdx.x * (blockDim.x >> 6) + w;
  if (cid >= nchains) return;

  long base = (long)cid * mpb;
  const uint4* pA = in_frags + (size_t)(2 * l) + (size_t)base * 128;
  const uint4* pB = pA + 1;

  uint4 bufA[8], bufB[8];
#pragma unroll
  for (int u = 0; u < 8; ++u) {
    bufA[u] = pA[(size_t)u * 128];
    bufB[u] = pB[(size_t)u * 128];
  }

  int col = l & 31, h = l >> 5;
  f32x16 acc, zero16;
#pragma unroll
  for (int r = 0; r < 16; ++r) {
    int row = (r & 3) + 8 * (r >> 2) + 4 * h;
    acc[r]  = (row == col) ? 1.f : 0.f;
    zero16[r] = 0.f;
  }

  float Eacc = 0.f;
  if (in_E) {
    for (int k = 0; k < mpb; ++k) Eacc += in_E[base + k];
  }

  for (int s = 0; s < mpb; s += 8) {
#pragma unroll
    for (int u = 0; u < 8; ++u) {
      uint4 B1, B2;
      acc_to_bops(acc, B1, B2);
      short8 A1 = __builtin_bit_cast(short8, bufA[u]);
      short8 A2 = __builtin_bit_cast(short8, bufB[u]);
      int nm = s + u + 8;
      if (nm < mpb) {
        bufA[u] = pA[(size_t)nm * 128];
        bufB[u] = pB[(size_t)nm * 128];
      }
      f32x16 t1 = __builtin_amdgcn_mfma_f32_32x32x16_bf16(
          A1, __builtin_bit_cast(short8, B1), zero16, 0, 0, 0);
      acc = __builtin_amdgcn_mfma_f32_32x32x16_bf16(
          A2, __builtin_bit_cast(short8, B2), t1, 0, 0, 0);
    }
    renorm(acc, Eacc);
  }

  if (out_final) {
#pragma unroll
    for (int r = 0; r < 16; ++r) {
      int row = (r & 3) + 8 * (r >> 2) + 4 * h;
      out_final[row * 32 + col] = acc[r];
    }
    if (l == 0) *out_E = Eacc;
  } else {
#pragma unroll
    for (int r = 0; r < 16; ++r) {
      int row = (r & 3) + 8 * (r >> 2) + 4 * h;
      int flat = (row + 32 * ((col >> 3) & 1)) * 16 + ((col >> 4) << 3) + (col & 7);
      out_frags[(size_t)cid * 1024 + flat] = f2bf(acc[r]);
    }
    if (l == 0) out_E[cid] = Eacc;
  }
}

// ---------------------------------------------------------------------------
// finalize (unchanged, verified).
// ---------------------------------------------------------------------------
__global__ __launch_bounds__(64) void finalize_kernel(
    const float* __restrict__ init_logits, const float* __restrict__ E,
    const float* __restrict__ Spart, int nSpart,
    const float* __restrict__ MT, const float* __restrict__ Egrand,
    float* __restrict__ out)
{
  int l = threadIdx.x;
  int j = l & 31;

  float il = init_logits[j];
  float mx = il;
#pragma unroll
  for (int m = 16; m >= 1; m >>= 1) mx = fmaxf(mx, __shfl_xor(mx, m, 32));
  float pz = __expf(il - mx);
  float sz = pz;
#pragma unroll
  for (int m = 16; m >= 1; m >>= 1) sz += __shfl_xor(sz, m, 32);
  float a0 = (pz / sz) * E[j];

  float rbuf[32];
  const float4* rowp = (const float4*)(MT + j * 32);
#pragma unroll
  for (int q = 0; q < 8; ++q) {
    float4 v = rowp[q];
    rbuf[4*q+0] = v.x; rbuf[4*q+1] = v.y; rbuf[4*q+2] = v.z; rbuf[4*q+3] = v.w;
  }
  float af = 0.f;
#pragma unroll
  for (int m = 0; m < 32; ++m) af = fmaf(__shfl(a0, m, 32), rbuf[m], af);

  float sa = af;
#pragma unroll
  for (int m = 16; m >= 1; m >>= 1) sa += __shfl_xor(sa, m, 32);

  double ss = 0.0;
  for (int idx = l; idx < nSpart; idx += 64) ss += (double)Spart[idx];
#pragma unroll
  for (int m = 32; m >= 1; m >>= 1) ss += __shfl_xor(ss, m, 64);

  if (l == 0) {
    double r = log((double)sa) + ss + 0.6931471805599453 * (double)(*Egrand);
    out[0] = (float)r;
  }
}

// ---------------------------------------------------------------------------
extern "C" void kernel_launch(void* const* d_in, const int* in_sizes, int n_in,
                              void* d_out, int out_size, void* d_ws, size_t ws_size,
                              hipStream_t stream) {
  const float* X   = (const float*)d_in[0];
  const float* Y   = (const float*)d_in[1];
  const float* il  = (const float*)d_in[2];
  const float* W   = (const float*)d_in[3];
  const float* b   = (const float*)d_in[4];
  const float* mu  = (const float*)d_in[5];
  const float* rlv = (const float*)d_in[6];
  float* out = (float*)d_out;

  int T   = in_sizes[0] / 16;
  int NB0 = (T + 63) / 64;
  int NC  = T / 64;   // L1 chains (2048 @ T=131072) — exact round-5 structure

  char* ws = (char*)d_ws;
  size_t off = 0;
  auto alloc = [&](size_t bytes) -> void* {
    void* p = ws + off;
    off = (off + bytes + 255) & ~(size_t)255;
    return p;
  };
  float* E      = (float*)alloc((size_t)T * 32 * 4);
  float* Spart  = (float*)alloc((size_t)NB0 * 4);
  u16*   Sg     = (u16*)  alloc((size_t)NC * 2048);
  float* Eg     = (float*)alloc((size_t)NC * 4);
  u16*   Rf     = (u16*)  alloc((size_t)64 * 2048);
  float* ER     = (float*)alloc((size_t)64 * 4);
  float* MT     = (float*)alloc(4096);
  float* Egrand = (float*)alloc(256);
  u16*   Wfrag  = (u16*)  alloc((size_t)16384 * 2);
  float* bprime = (float*)alloc((size_t)1024 * 4);

  prep_kernel<<<64, 256, 0, stream>>>(W, b, Wfrag, bprime);
  emis_kernel<<<NB0, 256, 0, stream>>>(Y, mu, rlv, T, E, Spart);

  // Fused: B-production + L1 chain, one wave per block, B never hits HBM.
  fused1w_kernel<<<NC, 64, 0, stream>>>(X, E, Wfrag, bprime, T, Sg, Eg);

  // L2: 64 chains of 32 over Sg (exact round-5 structure); L3: 1 chain of 64.
  chain_kernel<<<16, 256, 0, stream>>>((const uint4*)Sg, Eg, 64, NC / 64, Rf, ER, nullptr);
  chain_kernel<<<1, 64, 0, stream>>>((const uint4*)Rf, ER, 1, 64, nullptr, Egrand, MT);

  finalize_kernel<<<1, 64, 0, stream>>>(il, E, Spart, NB0, MT, Egrand, out);
}

// Round 9
// 149.362 us; speedup vs baseline: 1.5655x; 1.5655x over previous
//
#include <hip/hip_runtime.h>

typedef float  f32x16 __attribute__((ext_vector_type(16)));
typedef float  f32x2  __attribute__((ext_vector_type(2)));
typedef short  short8 __attribute__((ext_vector_type(8)));
typedef unsigned short u16;
typedef unsigned int   u32;

#define LOG2PI_F 1.8378770664093453f

__device__ __forceinline__ u16 f2bf(float f) {
  u32 u = __builtin_bit_cast(u32, f);
  u32 r = (u + 0x7FFFu + ((u >> 16) & 1u)) >> 16;
  return (u16)r;
}

// ---------------------------------------------------------------------------
// K0: emissions. E[t,j] = exp(log_em[t,j] - s_t), s_t = max_j log_em[t,j].
// ---------------------------------------------------------------------------
__global__ __launch_bounds__(256) void emis_kernel(
    const float* __restrict__ Y, const float* __restrict__ mu,
    const float* __restrict__ rlv, int T,
    float* __restrict__ E, float* __restrict__ Spart)
{
  int j  = threadIdx.x & 31;
  int ts = threadIdx.x >> 5;  // 0..7

  float muv[16], iv[16];
  float slv = 0.f;
  const float4* mp = (const float4*)(mu  + (size_t)j * 16);
  const float4* rp = (const float4*)(rlv + (size_t)j * 16);
#pragma unroll
  for (int q = 0; q < 4; ++q) {
    float4 m4 = mp[q], r4 = rp[q];
    float mm[4] = {m4.x, m4.y, m4.z, m4.w};
    float rr[4] = {r4.x, r4.y, r4.z, r4.w};
#pragma unroll
    for (int e = 0; e < 4; ++e) {
      float lv = fminf(fmaxf(rr[e], -6.f), 6.f);
      muv[4*q+e] = mm[e];
      iv[4*q+e]  = __expf(-lv);
      slv += lv;
    }
  }
  float base_c = 16.f * LOG2PI_F + slv;

  float sacc = 0.f;
  for (int p2 = 0; p2 < 8; ++p2) {
    int t = blockIdx.x * 64 + p2 * 8 + ts;
    if (t < T) {
      float quad = 0.f;
      const float4* yp = (const float4*)(Y + (size_t)t * 16);
#pragma unroll
      for (int q = 0; q < 4; ++q) {
        float4 y4 = yp[q];
        float yy[4] = {y4.x, y4.y, y4.z, y4.w};
#pragma unroll
        for (int e = 0; e < 4; ++e) {
          float d = yy[e] - muv[4*q+e];
          quad = fmaf(d * d, iv[4*q+e], quad);
        }
      }
      float lem = -0.5f * (base_c + quad);
      float mx = lem;
#pragma unroll
      for (int m = 16; m >= 1; m >>= 1) mx = fmaxf(mx, __shfl_xor(mx, m, 32));
      E[(size_t)t * 32 + j] = __expf(lem - mx);
      if (j == 0) sacc += mx;
    }
  }
  __shared__ float sred[8];
  if (j == 0) sred[ts] = sacc;
  __syncthreads();
  if (threadIdx.x == 0) {
    float s = 0.f;
#pragma unroll
    for (int k = 0; k < 8; ++k) s += sred[k];
    Spart[blockIdx.x] = s;
  }
}

// ---------------------------------------------------------------------------
// Prep: Wfrag = A-operand fragments of W/ln2 (bf16), bprime = b/ln2.
// ---------------------------------------------------------------------------
__global__ __launch_bounds__(256) void prep_kernel(
    const float* __restrict__ W, const float* __restrict__ b,
    u16* __restrict__ Wfrag, float* __restrict__ bprime)
{
  const float INVLN2 = 1.4426950408889634f;
  int idx = blockIdx.x * 256 + threadIdx.x;
  if (idx < 16384) {
    int i = idx >> 9, rem = idx & 511, l = rem >> 3, e = rem & 7;
    int j = l & 31, h = l >> 5;
    Wfrag[idx] = f2bf(W[i * 512 + j * 16 + h * 8 + e] * INVLN2);
  }
  if (idx < 1024) bprime[idx] = b[idx] * INVLN2;
}

// ---------------------------------------------------------------------------
// Shared primitives (hardware-verified rounds 0-8).
// ---------------------------------------------------------------------------
__device__ __forceinline__ void acc_to_bops(const f32x16& acc, uint4& B1, uint4& B2) {
  u32 pk[8];
#pragma unroll
  for (int q = 0; q < 8; ++q) {
    u32 r;
    asm("v_cvt_pk_bf16_f32 %0, %1, %2" : "=v"(r) : "v"(acc[2*q]), "v"(acc[2*q+1]));
    pk[q] = r;
  }
  asm("v_permlane32_swap_b32 %0, %1" : "+v"(pk[0]), "+v"(pk[2]));
  asm("v_permlane32_swap_b32 %0, %1" : "+v"(pk[1]), "+v"(pk[3]));
  B1 = make_uint4(pk[0], pk[1], pk[2], pk[3]);
  asm("v_permlane32_swap_b32 %0, %1" : "+v"(pk[4]), "+v"(pk[6]));
  asm("v_permlane32_swap_b32 %0, %1" : "+v"(pk[5]), "+v"(pk[7]));
  B2 = make_uint4(pk[4], pk[5], pk[6], pk[7]);
}

__device__ __forceinline__ void renorm(f32x16& acc, float& Eacc) {
  float m = acc[0];
#pragma unroll
  for (int r = 1; r < 16; ++r) m = fmaxf(m, acc[r]);
#pragma unroll
  for (int off = 32; off >= 1; off >>= 1) m = fmaxf(m, __shfl_xor(m, off, 64));
  if (m > 0.f) {
    int ex;
    frexpf(m, &ex);
    float sc = ldexpf(1.f, -ex);
#pragma unroll
    for (int r = 0; r < 16; ++r) acc[r] *= sc;
    Eacc += (float)ex;
  }
}

// fp8 chunk (8 e4m3 bytes in a uint2) -> 8 bf16 (uint4), byte order preserved.
__device__ __forceinline__ uint4 fp8x8_to_bf16x8(uint2 c) {
  f32x2 l0 = __builtin_amdgcn_cvt_pk_f32_fp8((int)c.x, false);
  f32x2 h0 = __builtin_amdgcn_cvt_pk_f32_fp8((int)c.x, true);
  f32x2 l1 = __builtin_amdgcn_cvt_pk_f32_fp8((int)c.y, false);
  f32x2 h1 = __builtin_amdgcn_cvt_pk_f32_fp8((int)c.y, true);
  u32 w0, w1, w2, w3;
  asm("v_cvt_pk_bf16_f32 %0, %1, %2" : "=v"(w0) : "v"(l0.x), "v"(l0.y));
  asm("v_cvt_pk_bf16_f32 %0, %1, %2" : "=v"(w1) : "v"(h0.x), "v"(h0.y));
  asm("v_cvt_pk_bf16_f32 %0, %1, %2" : "=v"(w2) : "v"(l1.x), "v"(l1.y));
  asm("v_cvt_pk_bf16_f32 %0, %1, %2" : "=v"(w3) : "v"(h1.x), "v"(h1.y));
  return make_uint4(w0, w1, w2, w3);
}

// ---------------------------------------------------------------------------
// Production batch (verified r2-r8 math), output packed fp8: q[r] = 4 e4m3
// bytes = B[t=tc][i=ib0..ib0+3][j(r,h)]. Identity override for t==0 applied
// at f32 level (exact in fp8).
// ---------------------------------------------------------------------------
__device__ __forceinline__ void bmat2_batch_fp8(
    const short8* wf, int ib0, short8 xf, const float* __restrict__ bprime,
    int h, const float* ee, int tglob, u32* q /* [16] */)
{
  f32x16 a[4];
#pragma unroll
  for (int e = 0; e < 4; ++e) {
    f32x16 c;
#pragma unroll
    for (int qd = 0; qd < 4; ++qd) {
      float4 b4 = *(const float4*)(bprime + (ib0 + e) * 32 + 4 * h + 8 * qd);
      c[4*qd+0] = b4.x; c[4*qd+1] = b4.y; c[4*qd+2] = b4.z; c[4*qd+3] = b4.w;
    }
    a[e] = __builtin_amdgcn_mfma_f32_32x32x16_bf16(wf[e], xf, c, 0, 0, 0);
  }
#pragma unroll
  for (int e = 0; e < 4; ++e) {
    float s = 0.f;
#pragma unroll
    for (int r = 0; r < 16; ++r) { float p = exp2f(a[e][r]); a[e][r] = p; s += p; }
    float s2 = s, s3 = s;
    asm("v_permlane32_swap_b32 %0, %1" : "+v"(s2), "+v"(s3));
    float rv = __builtin_amdgcn_rcpf(s2 + s3);
#pragma unroll
    for (int r = 0; r < 16; ++r) a[e][r] *= rv;
  }
#pragma unroll
  for (int r = 0; r < 16; ++r) {
    float e0 = a[0][r] * ee[r], e1 = a[1][r] * ee[r];
    float e2 = a[2][r] * ee[r], e3 = a[3][r] * ee[r];
    if (tglob == 0) {
      int j = 4 * h + 8 * (r >> 2) + (r & 3);
      e0 = (ib0 + 0 == j) ? 1.f : 0.f;
      e1 = (ib0 + 1 == j) ? 1.f : 0.f;
      e2 = (ib0 + 2 == j) ? 1.f : 0.f;
      e3 = (ib0 + 3 == j) ? 1.f : 0.f;
    }
    u32 v = (u32)__builtin_amdgcn_cvt_pk_fp8_f32(e0, e1, 0, false);
    v = (u32)__builtin_amdgcn_cvt_pk_fp8_f32(e2, e3, (int)v, true);
    q[r] = v;
  }
}

// ---------------------------------------------------------------------------
// fused1w: ONE WAVE per block (r8-green structure), block owns 64 t.
// Staging now fp8 (32KB/wave -> 5 blocks/CU) with chunk-index XOR swizzle
// (c ^ (matrix&15)) applied identically on write and read (same wave).
// Chain math verbatim (bf16 MFMA after upconvert). Levels = exact r5/r8.
// ---------------------------------------------------------------------------
__global__ __launch_bounds__(64) void fused1w_kernel(
    const float* __restrict__ X, const float* __restrict__ E,
    const u16* __restrict__ Wfrag, const float* __restrict__ bprime,
    int T, u16* __restrict__ Sg, float* __restrict__ Eg)
{
  __shared__ __align__(16) uint2 lds8[4096];  // 32 KB: 32 matrices x 128 fp8-chunks
  u32* lds32 = (u32*)lds8;
  int l = threadIdx.x, tc = l & 31, h = l >> 5;

  short8 wf[32];
#pragma unroll
  for (int it = 0; it < 32; ++it)
    wf[it] = *(const short8*)(Wfrag + ((size_t)it * 64 + l) * 8);

  f32x16 acc, zero16;
#pragma unroll
  for (int r = 0; r < 16; ++r) {
    int row = (r & 3) + 8 * (r >> 2) + 4 * h;
    acc[r]  = (row == tc) ? 1.f : 0.f;
    zero16[r] = 0.f;
  }
  float Eacc = 0.f;

  for (int grp = 0; grp < 2; ++grp) {
    int tglob = blockIdx.x * 64 + grp * 32 + tc;

    // ---- Phase P: production (verified math; fp8 pack; swizzled b32 writes) ----
    float4 xa = *(const float4*)(X + (size_t)tglob * 16 + 8 * h);
    float4 xb = *(const float4*)(X + (size_t)tglob * 16 + 8 * h + 4);
    u32 xp0, xp1, xp2, xp3;
    asm("v_cvt_pk_bf16_f32 %0, %1, %2" : "=v"(xp0) : "v"(xa.x), "v"(xa.y));
    asm("v_cvt_pk_bf16_f32 %0, %1, %2" : "=v"(xp1) : "v"(xa.z), "v"(xa.w));
    asm("v_cvt_pk_bf16_f32 %0, %1, %2" : "=v"(xp2) : "v"(xb.x), "v"(xb.y));
    asm("v_cvt_pk_bf16_f32 %0, %1, %2" : "=v"(xp3) : "v"(xb.z), "v"(xb.w));
    uint4 xu = make_uint4(xp0, xp1, xp2, xp3);
    short8 xf = __builtin_bit_cast(short8, xu);

    float ee[16];
#pragma unroll
    for (int qd = 0; qd < 4; ++qd) {
      float4 eq = *(const float4*)(E + (size_t)tglob * 32 + 4 * h + 8 * qd);
      ee[4*qd+0] = eq.x; ee[4*qd+1] = eq.y; ee[4*qd+2] = eq.z; ee[4*qd+3] = eq.w;
    }

#pragma unroll
    for (int b = 0; b < 4; ++b) {
      u32 q[16];
      // i = 8b..8b+3 -> low half of each chunk
      bmat2_batch_fp8(wf + 8*b, 8*b, xf, bprime, h, ee, tglob, q);
#pragma unroll
      for (int r = 0; r < 16; ++r) {
        int j = 4*h + 8*(r>>2) + (r&3);
        int c = (j + 32 * (b & 1)) * 2 + (b >> 1);      // verified chunk index
        lds32[(tc * 128 + (c ^ (tc & 15))) * 2] = q[r];
      }
      // i = 8b+4..8b+7 -> high half
      bmat2_batch_fp8(wf + 8*b + 4, 8*b + 4, xf, bprime, h, ee, tglob, q);
#pragma unroll
      for (int r = 0; r < 16; ++r) {
        int j = 4*h + 8*(r>>2) + (r&3);
        int c = (j + 32 * (b & 1)) * 2 + (b >> 1);
        lds32[(tc * 128 + (c ^ (tc & 15))) * 2 + 1] = q[r];
      }
    }
    __syncthreads();

    // ---- Phase C: chain the 32 matrices (verbatim step; fp8 upconvert) ----
#pragma unroll 4
    for (int k = 0; k < 32; ++k) {
      int s = k & 15;
      uint2 c0 = lds8[k * 128 + ((2 * l)     ^ s)];
      uint2 c1 = lds8[k * 128 + ((2 * l + 1) ^ s)];
      uint4 A1u = fp8x8_to_bf16x8(c0);
      uint4 A2u = fp8x8_to_bf16x8(c1);
      uint4 B1, B2;
      acc_to_bops(acc, B1, B2);
      f32x16 t1 = __builtin_amdgcn_mfma_f32_32x32x16_bf16(
          __builtin_bit_cast(short8, A1u), __builtin_bit_cast(short8, B1), zero16, 0, 0, 0);
      acc = __builtin_amdgcn_mfma_f32_32x32x16_bf16(
          __builtin_bit_cast(short8, A2u), __builtin_bit_cast(short8, B2), t1, 0, 0, 0);
      if ((k & 7) == 7) renorm(acc, Eacc);
    }
    __syncthreads();  // before next group's production overwrites LDS
  }

  // ---- epilogue: verbatim verified out_frags write ----
  int col = l & 31;
#pragma unroll
  for (int r = 0; r < 16; ++r) {
    int row = (r & 3) + 8 * (r >> 2) + 4 * h;
    int flat = (row + 32 * ((col >> 3) & 1)) * 16 + ((col >> 4) << 3) + (col & 7);
    Sg[(size_t)blockIdx.x * 1024 + flat] = f2bf(acc[r]);
  }
  if (l == 0) Eg[blockIdx.x] = Eacc;
}

// ---------------------------------------------------------------------------
// Chain kernel (levels 2-3; verified multi-wave form, matrix-major bf16).
// ---------------------------------------------------------------------------
__global__ void chain_kernel(
    const uint4* __restrict__ in_frags, const float* __restrict__ in_E,
    int nchains, int mpb, u16* __restrict__ out_frags,
    float* __restrict__ out_E, float* __restrict__ out_final)
{
  int w = threadIdx.x >> 6, l = threadIdx.x & 63;
  int cid = blockIdx.x * (blockDim.x >> 6) + w;
  if (cid >= nchains) return;

  long base = (long)cid * mpb;
  const uint4* pA = in_frags + (size_t)(2 * l) + (size_t)base * 128;
  const uint4* pB = pA + 1;

  uint4 bufA[8], bufB[8];
#pragma unroll
  for (int u = 0; u < 8; ++u) {
    bufA[u] = pA[(size_t)u * 128];
    bufB[u] = pB[(size_t)u * 128];
  }

  int col = l & 31, h = l >> 5;
  f32x16 acc, zero16;
#pragma unroll
  for (int r = 0; r < 16; ++r) {
    int row = (r & 3) + 8 * (r >> 2) + 4 * h;
    acc[r]  = (row == col) ? 1.f : 0.f;
    zero16[r] = 0.f;
  }

  float Eacc = 0.f;
  if (in_E) {
    for (int k = 0; k < mpb; ++k) Eacc += in_E[base + k];
  }

  for (int s = 0; s < mpb; s += 8) {
#pragma unroll
    for (int u = 0; u < 8; ++u) {
      uint4 B1, B2;
      acc_to_bops(acc, B1, B2);
      short8 A1 = __builtin_bit_cast(short8, bufA[u]);
      short8 A2 = __builtin_bit_cast(short8, bufB[u]);
      int nm = s + u + 8;
      if (nm < mpb) {
        bufA[u] = pA[(size_t)nm * 128];
        bufB[u] = pB[(size_t)nm * 128];
      }
      f32x16 t1 = __builtin_amdgcn_mfma_f32_32x32x16_bf16(
          A1, __builtin_bit_cast(short8, B1), zero16, 0, 0, 0);
      acc = __builtin_amdgcn_mfma_f32_32x32x16_bf16(
          A2, __builtin_bit_cast(short8, B2), t1, 0, 0, 0);
    }
    renorm(acc, Eacc);
  }

  if (out_final) {
#pragma unroll
    for (int r = 0; r < 16; ++r) {
      int row = (r & 3) + 8 * (r >> 2) + 4 * h;
      out_final[row * 32 + col] = acc[r];
    }
    if (l == 0) *out_E = Eacc;
  } else {
#pragma unroll
    for (int r = 0; r < 16; ++r) {
      int row = (r & 3) + 8 * (r >> 2) + 4 * h;
      int flat = (row + 32 * ((col >> 3) & 1)) * 16 + ((col >> 4) << 3) + (col & 7);
      out_frags[(size_t)cid * 1024 + flat] = f2bf(acc[r]);
    }
    if (l == 0) out_E[cid] = Eacc;
  }
}

// ---------------------------------------------------------------------------
// finalize (unchanged, verified).
// ---------------------------------------------------------------------------
__global__ __launch_bounds__(64) void finalize_kernel(
    const float* __restrict__ init_logits, const float* __restrict__ E,
    const float* __restrict__ Spart, int nSpart,
    const float* __restrict__ MT, const float* __restrict__ Egrand,
    float* __restrict__ out)
{
  int l = threadIdx.x;
  int j = l & 31;

  float il = init_logits[j];
  float mx = il;
#pragma unroll
  for (int m = 16; m >= 1; m >>= 1) mx = fmaxf(mx, __shfl_xor(mx, m, 32));
  float pz = __expf(il - mx);
  float sz = pz;
#pragma unroll
  for (int m = 16; m >= 1; m >>= 1) sz += __shfl_xor(sz, m, 32);
  float a0 = (pz / sz) * E[j];

  float rbuf[32];
  const float4* rowp = (const float4*)(MT + j * 32);
#pragma unroll
  for (int q = 0; q < 8; ++q) {
    float4 v = rowp[q];
    rbuf[4*q+0] = v.x; rbuf[4*q+1] = v.y; rbuf[4*q+2] = v.z; rbuf[4*q+3] = v.w;
  }
  float af = 0.f;
#pragma unroll
  for (int m = 0; m < 32; ++m) af = fmaf(__shfl(a0, m, 32), rbuf[m], af);

  float sa = af;
#pragma unroll
  for (int m = 16; m >= 1; m >>= 1) sa += __shfl_xor(sa, m, 32);

  double ss = 0.0;
  for (int idx = l; idx < nSpart; idx += 64) ss += (double)Spart[idx];
#pragma unroll
  for (int m = 32; m >= 1; m >>= 1) ss += __shfl_xor(ss, m, 64);

  if (l == 0) {
    double r = log((double)sa) + ss + 0.6931471805599453 * (double)(*Egrand);
    out[0] = (float)r;
  }
}

// ---------------------------------------------------------------------------
extern "C" void kernel_launch(void* const* d_in, const int* in_sizes, int n_in,
                              void* d_out, int out_size, void* d_ws, size_t ws_size,
                              hipStream_t stream) {
  const float* X   = (const float*)d_in[0];
  const float* Y   = (const float*)d_in[1];
  const float* il  = (const float*)d_in[2];
  const float* W   = (const float*)d_in[3];
  const float* b   = (const float*)d_in[4];
  const float* mu  = (const float*)d_in[5];
  const float* rlv = (const float*)d_in[6];
  float* out = (float*)d_out;

  int T   = in_sizes[0] / 16;
  int NB0 = (T + 63) / 64;
  int NC  = T / 64;   // L1 chains (2048 @ T=131072) — exact r5/r8 structure

  char* ws = (char*)d_ws;
  size_t off = 0;
  auto alloc = [&](size_t bytes) -> void* {
    void* p = ws + off;
    off = (off + bytes + 255) & ~(size_t)255;
    return p;
  };
  float* E      = (float*)alloc((size_t)T * 32 * 4);
  float* Spart  = (float*)alloc((size_t)NB0 * 4);
  u16*   Sg     = (u16*)  alloc((size_t)NC * 2048);
  float* Eg     = (float*)alloc((size_t)NC * 4);
  u16*   Rf     = (u16*)  alloc((size_t)64 * 2048);
  float* ER     = (float*)alloc((size_t)64 * 4);
  float* MT     = (float*)alloc(4096);
  float* Egrand = (float*)alloc(256);
  u16*   Wfrag  = (u16*)  alloc((size_t)16384 * 2);
  float* bprime = (float*)alloc((size_t)1024 * 4);

  prep_kernel<<<64, 256, 0, stream>>>(W, b, Wfrag, bprime);
  emis_kernel<<<NB0, 256, 0, stream>>>(Y, mu, rlv, T, E, Spart);

  // Fused: B-production + L1 chain, one wave per block, fp8 LDS staging.
  fused1w_kernel<<<NC, 64, 0, stream>>>(X, E, Wfrag, bprime, T, Sg, Eg);

  // L2: 64 chains of 32 over Sg; L3: 1 chain of 64 (exact r5/r8 structure).
  chain_kernel<<<16, 256, 0, stream>>>((const uint4*)Sg, Eg, 64, NC / 64, Rf, ER, nullptr);
  chain_kernel<<<1, 64, 0, stream>>>((const uint4*)Rf, ER, 1, 64, nullptr, Egrand, MT);

  finalize_kernel<<<1, 64, 0, stream>>>(il, E, Spart, NB0, MT, Egrand, out);
}